// Round 9
// baseline (481.462 us; speedup 1.0000x reference)
//
#include <hip/hip_runtime.h>

#define N_ATOM 30000
#define N_PAIR 1000000
#define N_TRI  4000000
#define N_SF   16
#define FP_ELEMS (N_ATOM * N_SF)

#define ASH  5                      // atoms per coarse bucket = 32
#define APB  32
#define NCB  938                    // ceil(30000/32)
#define NSUB 8                      // segments per coarse bucket
#define NSEG (NCB * NSUB)           // 7504
#define OVF_CNT_IDX NSEG
#define OVF_CAP 131072
#define TILE 8192
#define PER_TH 16                   // 512 threads * 16 = 8192
#define NTILES ((N_TRI + TILE - 1) / TILE)   // 489

// workspace layout (bytes)
#define OFF_CCNT  0ULL              //  32 KiB: NSEG+1 ints
#define OFF_IKMAX 65536ULL          //  4,000,000  (int per pair)
#define OFF_AOFP  4065536ULL        //  2,000,000  (ushort per pair)
#define OFF_FLAG  6065536ULL        //  1,000,000  (byte per pair)
#define OFF_OVF   7065536ULL        //  1,048,576  (int2 * 131072)
#define OFF_PACK  8114112ULL        // 16,000,000  (float4 {dx,dy,dz,fc})
#define OFF_CB    24114112ULL       // cbucket: NSEG * cap * 8

__device__ __constant__ float c_eta[16] = {
    0.01f, 0.014f, 0.02f, 0.028f, 0.04f, 0.056f, 0.08f, 0.11f,
    0.16f, 0.22f, 0.32f, 0.45f, 0.63f, 0.72f, 0.9f, 1.0f};

// ---------------------------------------------------------------------------
__device__ __forceinline__ bool tri_math_pack(
    float4 A, float4 B, float A8[8], float& R2)
{
    float ax = A.x, ay = A.y, az = A.z, fcij = A.w;
    float bx = B.x, by = B.y, bz = B.z, fcik = B.w;
    float d2ij = fmaf(ax, ax, fmaf(ay, ay, az * az));
    float d2ik = fmaf(bx, bx, fmaf(by, by, bz * bz));
    float jx = bx - ax, jy = by - ay, jz = bz - az;
    float d2jk = fmaf(jx, jx, fmaf(jy, jy, jz * jz));
    if (!(d2jk < 36.0f)) return false;
    float dij = sqrtf(d2ij);
    float dik = sqrtf(d2ik);
    float djk = sqrtf(d2jk);
    const float PI_OVER_RC = 0.5235987755982988f;
    float fcjk = 0.5f * (__cosf(PI_OVER_RC * djk) + 1.0f);
    float dot = fmaf(ax, bx, fmaf(ay, by, az * bz));
    float cosv = dot / (dij * dik);
    R2 = d2ij + d2ik + d2jk;
    float FCt = fcij * fcik * fcjk;
    float bm = fmaxf(1.0f - cosv, 0.0f);
    float bp = fmaxf(1.0f + cosv, 0.0f);
    float bm2 = bm * bm, bp2 = bp * bp;
    float bm4 = bm2 * bm2, bp4 = bp2 * bp2;
    float bm8 = bm4 * bm4, bp8 = bp4 * bp4;
    A8[0] = FCt * bm;              A8[1] = FCt * bp;
    A8[2] = 0.5f * FCt * bm2;      A8[3] = 0.5f * FCt * bp2;
    A8[4] = 0.125f * FCt * bm4;    A8[5] = 0.125f * FCt * bp4;
    A8[6] = 0.0078125f * FCt * bm8; A8[7] = 0.0078125f * FCt * bp8;
    return true;
}

// ---------------------------------------------------------------------------
// fast path
// ---------------------------------------------------------------------------

__global__ __launch_bounds__(256) void prep2(
    const int2* __restrict__ ind2, const float* __restrict__ diff,
    const float* __restrict__ fc,
    int* __restrict__ ccnt, int* __restrict__ ikmax,
    unsigned short* __restrict__ aofp, unsigned char* __restrict__ flag,
    float4* __restrict__ pack, float* __restrict__ out)
{
    int p = blockIdx.x * blockDim.x + threadIdx.x;
    if (p <= NSEG) ccnt[p] = 0;
    if (p < FP_ELEMS) out[p] = 0.0f;
    if (p >= N_PAIR) return;
    ikmax[p] = -1;
    flag[p] = 0;
    aofp[p] = (unsigned short)ind2[p].x;
    float4 r;
    r.x = diff[3 * p + 0];
    r.y = diff[3 * p + 1];
    r.z = diff[3 * p + 2];
    r.w = fc[p];
    pack[p] = r;
}

// LDS-staged counting scatter into coarse buckets.
__global__ __launch_bounds__(512) void bin3(
    const int2* __restrict__ ind3, const unsigned short* __restrict__ aofp,
    int* __restrict__ ccnt, int2* __restrict__ cbucket,
    int2* __restrict__ ovf, int cap)
{
    __shared__ int lcnt[NCB];
    __shared__ int lbase[NCB];
    const int thr = threadIdx.x;
    const int sub = blockIdx.x & (NSUB - 1);
    const long long t0 = (long long)blockIdx.x * TILE;

    for (int i = thr; i < NCB; i += 512) lcnt[i] = 0;
    __syncthreads();

    unsigned mypack[PER_TH];        // (slot<<15) | atom
#pragma unroll
    for (int j = 0; j < PER_TH; ++j) {
        long long t = t0 + j * 512 + thr;
        unsigned mp = 0;
        if (t < N_TRI) {
            int ij = ind3[t].x;
            int a = aofp[ij];
            int s = atomicAdd(&lcnt[a >> ASH], 1);
            mp = ((unsigned)s << 15) | (unsigned)a;
        }
        mypack[j] = mp;
    }
    __syncthreads();
    for (int c = thr; c < NCB; c += 512) {
        int n = lcnt[c];
        lbase[c] = n ? atomicAdd(&ccnt[c * NSUB + sub], n) : 0;
    }
    __syncthreads();
#pragma unroll
    for (int j = 0; j < PER_TH; ++j) {
        long long t = t0 + j * 512 + thr;
        if (t >= N_TRI) continue;
        unsigned mp = mypack[j];
        int a = (int)(mp & 0x7FFF);
        int c = a >> ASH;
        int slot = lbase[c] + (int)(mp >> 15);
        int2 pr = ind3[t];
        if (slot < cap) {
            int2 e;
            e.x = pr.x | ((a & (APB - 1)) << 20);
            e.y = pr.y;
            cbucket[(size_t)(c * NSUB + sub) * cap + slot] = e;
        } else {
            int o = atomicAdd(&ccnt[OVF_CNT_IDX], 1);
            if (o < OVF_CAP) ovf[o] = pr;
        }
    }
}

// 256-thr blocks, 2 blocks per coarse bucket (block handles 4 of 8 segments).
// 1876 blocks -> ~7.3 blocks/CU (no quantization cliff). LDS 32x16 acc,
// epilogue = 512 fire-and-forget unsafeAtomicAdd into prep-zeroed rows.
// Monotone pre-checks skip most memory-side atomicMax / flag RMWs.
__global__ __launch_bounds__(256) void reduce8(
    const int* __restrict__ ccnt, const int2* __restrict__ cbucket, int cap,
    const float4* __restrict__ pack,
    int* __restrict__ ikmax, unsigned char* __restrict__ flag,
    float* __restrict__ out)
{
    __shared__ float lacc[APB * 17];
    const int thr = threadIdx.x;
    const int w = thr >> 6, lane = thr & 63;
    const int b = blockIdx.x >> 1;
    const int h = blockIdx.x & 1;
    for (int i = thr; i < APB * 17; i += 256) lacc[i] = 0.0f;
    __syncthreads();

    const int seg = (b << 3) + (h << 2) + w;
    int n = min(ccnt[seg], cap);
    const long long* segq = (const long long*)(cbucket + (size_t)seg * cap);

    for (int i = lane; i < n; i += 64) {
        long long raw = __builtin_nontemporal_load(segq + i);  // read-once stream
        int ex = (int)(unsigned)(raw & 0xFFFFFFFFll);
        int ik = (int)(unsigned)((unsigned long long)raw >> 32);
        int a5 = (ex >> 20) & (APB - 1);
        int ij = ex & 0xFFFFF;
        float4 A = pack[ij];
        float4 B = pack[ik];
        float A8[8], R2;
        if (!tri_math_pack(A, B, A8, R2)) continue;
        if (!flag[ij]) flag[ij] = 1;           // idempotent; skip if set
        int nv = (b << ASH) + a5;
        if (ikmax[ik] < nv) atomicMax(&ikmax[ik], nv);  // monotone pre-check
#pragma unroll
        for (int s = 0; s < 16; ++s)
            atomicAdd(&lacc[a5 * 17 + s], A8[s & 7] * __expf(-c_eta[s] * R2));
    }
    __syncthreads();
    for (int t = thr; t < APB * N_SF; t += 256) {
        int atom = (b << ASH) + (t >> 4);
        float v = lacc[(t >> 4) * 17 + (t & 15)];
        if (atom < N_ATOM && v != 0.0f)
            unsafeAtomicAdd(out + (size_t)atom * N_SF + (t & 15), v);
    }
}

// exact path for bucket-overflow triplets (atomic adds; order-free)
__global__ __launch_bounds__(256) void ovf3(
    const int* __restrict__ ccnt, const int2* __restrict__ ovf,
    const float4* __restrict__ pack, const unsigned short* __restrict__ aofp,
    int* __restrict__ ikmax, unsigned char* __restrict__ flag,
    float* __restrict__ out)
{
    int i = blockIdx.x * blockDim.x + threadIdx.x;
    int n = ccnt[OVF_CNT_IDX];
    if (n > OVF_CAP) n = OVF_CAP;
    if (i >= n) return;
    int2 pr = ovf[i];
    int ij = pr.x, ik = pr.y;
    float A8[8], R2;
    if (!tri_math_pack(pack[ij], pack[ik], A8, R2)) return;
    int atom = aofp[ij];
    if (!flag[ij]) flag[ij] = 1;
    if (ikmax[ik] < atom) atomicMax(&ikmax[ik], atom);
    float* base = out + (size_t)atom * N_SF;
#pragma unroll
    for (int s = 0; s < 16; ++s)
        unsafeAtomicAdd(base + s, A8[s & 7] * __expf(-c_eta[s] * R2));
}

__global__ __launch_bounds__(256) void fin3(
    const int* __restrict__ ikmax, const unsigned char* __restrict__ flag,
    const unsigned short* __restrict__ aofp, float* __restrict__ out)
{
    int p = blockIdx.x * blockDim.x + threadIdx.x;
    if (p >= N_PAIR) return;
    int v = ikmax[p];
    if (flag[p]) { int a = aofp[p]; v = v > a ? v : a; }
    float* jf = out + FP_ELEMS;
    jf[2 * p + 0] = (float)p;
    jf[2 * p + 1] = (float)v;
}

// ---------------------------------------------------------------------------
// legacy fallback
// ---------------------------------------------------------------------------

__global__ __launch_bounds__(256) void init_legacy(float* __restrict__ out) {
    int i = blockIdx.x * blockDim.x + threadIdx.x;
    if (i < FP_ELEMS) out[i] = 0.0f;
    if (i < N_PAIR) ((int*)out + FP_ELEMS)[2 * i + 1] = -1;
}

__global__ __launch_bounds__(256) void tri_legacy(
    const int* __restrict__ ind2, const int2* __restrict__ ind3,
    const float* __restrict__ dist, const float* __restrict__ diff,
    const float* __restrict__ fc, float* __restrict__ out) {
    int t = blockIdx.x * blockDim.x + threadIdx.x;
    if (t >= N_TRI) return;
    int2 pr = ind3[t];
    int ij = pr.x, ik = pr.y;
    float4 A, B;
    A.x = diff[3 * ij + 0]; A.y = diff[3 * ij + 1]; A.z = diff[3 * ij + 2]; A.w = fc[ij];
    B.x = diff[3 * ik + 0]; B.y = diff[3 * ik + 1]; B.z = diff[3 * ik + 2]; B.w = fc[ik];
    float A8[8], R2;
    if (!tri_math_pack(A, B, A8, R2)) return;
    int atom = ind2[2 * ij];
    int* jac = (int*)out + FP_ELEMS;
    atomicMax(&jac[2 * ij + 1], atom);
    atomicMax(&jac[2 * ik + 1], atom);
    float* base = out + (size_t)atom * N_SF;
#pragma unroll
    for (int s = 0; s < 16; ++s)
        unsafeAtomicAdd(base + s, A8[s & 7] * __expf(-c_eta[s] * R2));
}

__global__ __launch_bounds__(256) void fin_legacy(float* __restrict__ out) {
    int p = blockIdx.x * blockDim.x + threadIdx.x;
    if (p >= N_PAIR) return;
    int* jac = (int*)out + FP_ELEMS;
    int v = jac[2 * p + 1];
    float* jf = (float*)jac;
    jf[2 * p + 0] = (float)p;
    jf[2 * p + 1] = (float)v;
}

// ---------------------------------------------------------------------------

extern "C" void kernel_launch(void* const* d_in, const int* in_sizes, int n_in,
                              void* d_out, int out_size, void* d_ws, size_t ws_size,
                              hipStream_t stream) {
    const int2*  ind2 = (const int2*)d_in[0];
    const int2*  ind3 = (const int2*)d_in[1];
    const float* dist = (const float*)d_in[2];
    const float* diff = (const float*)d_in[3];
    const float* fc   = (const float*)d_in[5];
    float* out = (float*)d_out;

    const size_t seg_stride = (size_t)NSEG * sizeof(int2);
    const size_t need_min = OFF_CB + seg_stride * 608;

    if (ws_size >= need_min) {
        char* ws = (char*)d_ws;
        int* ccnt            = (int*)(ws + OFF_CCNT);
        int* ikmax           = (int*)(ws + OFF_IKMAX);
        unsigned short* aofp = (unsigned short*)(ws + OFF_AOFP);
        unsigned char* flag  = (unsigned char*)(ws + OFF_FLAG);
        int2* ovf            = (int2*)(ws + OFF_OVF);
        float4* pack         = (float4*)(ws + OFF_PACK);
        int2* cbucket        = (int2*)(ws + OFF_CB);
        int cap = (int)((ws_size - OFF_CB) / seg_stride);
        if (cap > 1024) cap = 1024;

        int pb = (N_PAIR + 255) / 256;
        prep2<<<pb, 256, 0, stream>>>(ind2, diff, fc, ccnt, ikmax, aofp, flag, pack, out);
        bin3<<<NTILES, 512, 0, stream>>>(ind3, aofp, ccnt, cbucket, ovf, cap);
        reduce8<<<NCB * 2, 256, 0, stream>>>(ccnt, cbucket, cap, pack, ikmax, flag, out);
        ovf3<<<OVF_CAP / 256, 256, 0, stream>>>(ccnt, ovf, pack, aofp, ikmax, flag, out);
        fin3<<<pb, 256, 0, stream>>>(ikmax, flag, aofp, out);
    } else {
        init_legacy<<<(N_PAIR + 255) / 256, 256, 0, stream>>>(out);
        tri_legacy<<<(N_TRI + 255) / 256, 256, 0, stream>>>((const int*)d_in[0], ind3, dist, diff, fc, out);
        fin_legacy<<<(N_PAIR + 255) / 256, 256, 0, stream>>>(out);
    }
}

// Round 10
// 452.055 us; speedup vs baseline: 1.0651x; 1.0651x over previous
//
#include <hip/hip_runtime.h>

#define N_ATOM 30000
#define N_PAIR 1000000
#define N_TRI  4000000
#define N_SF   16
#define FP_ELEMS (N_ATOM * N_SF)

#define ASH  5                      // atoms per coarse bucket = 32
#define APB  32
#define NCB  938                    // ceil(30000/32)
#define NSUB 8                      // segments per coarse bucket
#define NSEG (NCB * NSUB)           // 7504
#define OVF_CNT_IDX NSEG
#define OVF_CAP 131072
#define TILE 8192
#define PER_TH 16                   // 512 threads * 16 = 8192
#define NTILES ((N_TRI + TILE - 1) / TILE)   // 489

// workspace layout (bytes)
#define OFF_CCNT  0ULL              //  32 KiB: NSEG+1 ints
#define OFF_IKMAX 65536ULL          //  4,000,000  (int per pair)
#define OFF_AOFP  4065536ULL        //  2,000,000  (ushort per pair)
#define OFF_FLAG  6065536ULL        //  1,000,000  (byte per pair)
#define OFF_OVF   7065536ULL        //  1,048,576  (int2 * 131072)
#define OFF_PACK  8114112ULL        // 16,000,000  (float4 {dx,dy,dz,fc})
#define OFF_CB    24114112ULL       // cbucket: NSEG * cap * 8

__device__ __constant__ float c_eta[16] = {
    0.01f, 0.014f, 0.02f, 0.028f, 0.04f, 0.056f, 0.08f, 0.11f,
    0.16f, 0.22f, 0.32f, 0.45f, 0.63f, 0.72f, 0.9f, 1.0f};

// ---------------------------------------------------------------------------
__device__ __forceinline__ bool tri_math_pack(
    float4 A, float4 B, float A8[8], float& R2)
{
    float ax = A.x, ay = A.y, az = A.z, fcij = A.w;
    float bx = B.x, by = B.y, bz = B.z, fcik = B.w;
    float d2ij = fmaf(ax, ax, fmaf(ay, ay, az * az));
    float d2ik = fmaf(bx, bx, fmaf(by, by, bz * bz));
    float jx = bx - ax, jy = by - ay, jz = bz - az;
    float d2jk = fmaf(jx, jx, fmaf(jy, jy, jz * jz));
    if (!(d2jk < 36.0f)) return false;
    float dij = sqrtf(d2ij);
    float dik = sqrtf(d2ik);
    float djk = sqrtf(d2jk);
    const float PI_OVER_RC = 0.5235987755982988f;
    float fcjk = 0.5f * (__cosf(PI_OVER_RC * djk) + 1.0f);
    float dot = fmaf(ax, bx, fmaf(ay, by, az * bz));
    float cosv = dot / (dij * dik);
    R2 = d2ij + d2ik + d2jk;
    float FCt = fcij * fcik * fcjk;
    float bm = fmaxf(1.0f - cosv, 0.0f);
    float bp = fmaxf(1.0f + cosv, 0.0f);
    float bm2 = bm * bm, bp2 = bp * bp;
    float bm4 = bm2 * bm2, bp4 = bp2 * bp2;
    float bm8 = bm4 * bm4, bp8 = bp4 * bp4;
    A8[0] = FCt * bm;              A8[1] = FCt * bp;
    A8[2] = 0.5f * FCt * bm2;      A8[3] = 0.5f * FCt * bp2;
    A8[4] = 0.125f * FCt * bm4;    A8[5] = 0.125f * FCt * bp4;
    A8[6] = 0.0078125f * FCt * bm8; A8[7] = 0.0078125f * FCt * bp8;
    return true;
}

// ---------------------------------------------------------------------------
// fast path
// ---------------------------------------------------------------------------

__global__ __launch_bounds__(256) void prep2(
    const int2* __restrict__ ind2, const float* __restrict__ diff,
    const float* __restrict__ fc,
    int* __restrict__ ccnt, int* __restrict__ ikmax,
    unsigned short* __restrict__ aofp, unsigned char* __restrict__ flag,
    float4* __restrict__ pack, float* __restrict__ out)
{
    int p = blockIdx.x * blockDim.x + threadIdx.x;
    if (p <= NSEG) ccnt[p] = 0;
    if (p < FP_ELEMS) out[p] = 0.0f;
    if (p >= N_PAIR) return;
    ikmax[p] = -1;
    flag[p] = 0;
    aofp[p] = (unsigned short)ind2[p].x;
    float4 r;
    r.x = diff[3 * p + 0];
    r.y = diff[3 * p + 1];
    r.z = diff[3 * p + 2];
    r.w = fc[p];
    pack[p] = r;
}

// LDS-staged counting scatter into coarse buckets.
__global__ __launch_bounds__(512) void bin3(
    const int2* __restrict__ ind3, const unsigned short* __restrict__ aofp,
    int* __restrict__ ccnt, int2* __restrict__ cbucket,
    int2* __restrict__ ovf, int cap)
{
    __shared__ int lcnt[NCB];
    __shared__ int lbase[NCB];
    const int thr = threadIdx.x;
    const int sub = blockIdx.x & (NSUB - 1);
    const long long t0 = (long long)blockIdx.x * TILE;

    for (int i = thr; i < NCB; i += 512) lcnt[i] = 0;
    __syncthreads();

    unsigned mypack[PER_TH];        // (slot<<15) | atom
#pragma unroll
    for (int j = 0; j < PER_TH; ++j) {
        long long t = t0 + j * 512 + thr;
        unsigned mp = 0;
        if (t < N_TRI) {
            int ij = ind3[t].x;
            int a = aofp[ij];
            int s = atomicAdd(&lcnt[a >> ASH], 1);
            mp = ((unsigned)s << 15) | (unsigned)a;
        }
        mypack[j] = mp;
    }
    __syncthreads();
    for (int c = thr; c < NCB; c += 512) {
        int n = lcnt[c];
        lbase[c] = n ? atomicAdd(&ccnt[c * NSUB + sub], n) : 0;
    }
    __syncthreads();
#pragma unroll
    for (int j = 0; j < PER_TH; ++j) {
        long long t = t0 + j * 512 + thr;
        if (t >= N_TRI) continue;
        unsigned mp = mypack[j];
        int a = (int)(mp & 0x7FFF);
        int c = a >> ASH;
        int slot = lbase[c] + (int)(mp >> 15);
        int2 pr = ind3[t];
        if (slot < cap) {
            int2 e;
            e.x = pr.x | ((a & (APB - 1)) << 20);
            e.y = pr.y;
            cbucket[(size_t)(c * NSUB + sub) * cap + slot] = e;
        } else {
            int o = atomicAdd(&ccnt[OVF_CNT_IDX], 1);
            if (o < OVF_CAP) ovf[o] = pr;
        }
    }
}

// r7's clean loop body on r8's grid: 1876 blocks x 256 thr (2 blocks per
// coarse bucket, each owning 4 segments' worth via h; ~7.3 blocks/CU).
// No pre-check reads (r9 lesson: they double FETCH). Epilogue: 512
// fire-and-forget unsafeAtomicAdd into prep-zeroed rows.
__global__ __launch_bounds__(256) void reduce9(
    const int* __restrict__ ccnt, const int2* __restrict__ cbucket, int cap,
    const float4* __restrict__ pack,
    int* __restrict__ ikmax, unsigned char* __restrict__ flag,
    float* __restrict__ out)
{
    __shared__ float lacc[APB * 17];
    const int thr = threadIdx.x;
    const int w = thr >> 6, lane = thr & 63;
    const int b = blockIdx.x >> 1;
    const int h = blockIdx.x & 1;
    for (int i = thr; i < APB * 17; i += 256) lacc[i] = 0.0f;
    __syncthreads();

    const int seg = (b << 3) + (h << 2) + w;
    int n = min(ccnt[seg], cap);
    const int2* segp = cbucket + (size_t)seg * cap;

    for (int i = lane; i < n; i += 64) {
        int2 e = segp[i];
        int a5 = (e.x >> 20) & (APB - 1);
        int ij = e.x & 0xFFFFF;
        int ik = e.y;
        float4 A = pack[ij];
        float4 B = pack[ik];
        float A8[8], R2;
        if (!tri_math_pack(A, B, A8, R2)) continue;
        flag[ij] = 1;
        atomicMax(&ikmax[ik], (b << ASH) + a5);
#pragma unroll
        for (int s = 0; s < 16; ++s)
            atomicAdd(&lacc[a5 * 17 + s], A8[s & 7] * __expf(-c_eta[s] * R2));
    }
    __syncthreads();
    for (int t = thr; t < APB * N_SF; t += 256) {
        int atom = (b << ASH) + (t >> 4);
        float v = lacc[(t >> 4) * 17 + (t & 15)];
        if (atom < N_ATOM && v != 0.0f)
            unsafeAtomicAdd(out + (size_t)atom * N_SF + (t & 15), v);
    }
}

// exact path for bucket-overflow triplets (atomic adds; order-free)
__global__ __launch_bounds__(256) void ovf3(
    const int* __restrict__ ccnt, const int2* __restrict__ ovf,
    const float4* __restrict__ pack, const unsigned short* __restrict__ aofp,
    int* __restrict__ ikmax, unsigned char* __restrict__ flag,
    float* __restrict__ out)
{
    int i = blockIdx.x * blockDim.x + threadIdx.x;
    int n = ccnt[OVF_CNT_IDX];
    if (n > OVF_CAP) n = OVF_CAP;
    if (i >= n) return;
    int2 pr = ovf[i];
    int ij = pr.x, ik = pr.y;
    float A8[8], R2;
    if (!tri_math_pack(pack[ij], pack[ik], A8, R2)) return;
    int atom = aofp[ij];
    flag[ij] = 1;
    atomicMax(&ikmax[ik], atom);
    float* base = out + (size_t)atom * N_SF;
#pragma unroll
    for (int s = 0; s < 16; ++s)
        unsafeAtomicAdd(base + s, A8[s & 7] * __expf(-c_eta[s] * R2));
}

__global__ __launch_bounds__(256) void fin3(
    const int* __restrict__ ikmax, const unsigned char* __restrict__ flag,
    const unsigned short* __restrict__ aofp, float* __restrict__ out)
{
    int p = blockIdx.x * blockDim.x + threadIdx.x;
    if (p >= N_PAIR) return;
    int v = ikmax[p];
    if (flag[p]) { int a = aofp[p]; v = v > a ? v : a; }
    float* jf = out + FP_ELEMS;
    jf[2 * p + 0] = (float)p;
    jf[2 * p + 1] = (float)v;
}

// ---------------------------------------------------------------------------
// legacy fallback
// ---------------------------------------------------------------------------

__global__ __launch_bounds__(256) void init_legacy(float* __restrict__ out) {
    int i = blockIdx.x * blockDim.x + threadIdx.x;
    if (i < FP_ELEMS) out[i] = 0.0f;
    if (i < N_PAIR) ((int*)out + FP_ELEMS)[2 * i + 1] = -1;
}

__global__ __launch_bounds__(256) void tri_legacy(
    const int* __restrict__ ind2, const int2* __restrict__ ind3,
    const float* __restrict__ dist, const float* __restrict__ diff,
    const float* __restrict__ fc, float* __restrict__ out) {
    int t = blockIdx.x * blockDim.x + threadIdx.x;
    if (t >= N_TRI) return;
    int2 pr = ind3[t];
    int ij = pr.x, ik = pr.y;
    float4 A, B;
    A.x = diff[3 * ij + 0]; A.y = diff[3 * ij + 1]; A.z = diff[3 * ij + 2]; A.w = fc[ij];
    B.x = diff[3 * ik + 0]; B.y = diff[3 * ik + 1]; B.z = diff[3 * ik + 2]; B.w = fc[ik];
    float A8[8], R2;
    if (!tri_math_pack(A, B, A8, R2)) return;
    int atom = ind2[2 * ij];
    int* jac = (int*)out + FP_ELEMS;
    atomicMax(&jac[2 * ij + 1], atom);
    atomicMax(&jac[2 * ik + 1], atom);
    float* base = out + (size_t)atom * N_SF;
#pragma unroll
    for (int s = 0; s < 16; ++s)
        unsafeAtomicAdd(base + s, A8[s & 7] * __expf(-c_eta[s] * R2));
}

__global__ __launch_bounds__(256) void fin_legacy(float* __restrict__ out) {
    int p = blockIdx.x * blockDim.x + threadIdx.x;
    if (p >= N_PAIR) return;
    int* jac = (int*)out + FP_ELEMS;
    int v = jac[2 * p + 1];
    float* jf = (float*)jac;
    jf[2 * p + 0] = (float)p;
    jf[2 * p + 1] = (float)v;
}

// ---------------------------------------------------------------------------

extern "C" void kernel_launch(void* const* d_in, const int* in_sizes, int n_in,
                              void* d_out, int out_size, void* d_ws, size_t ws_size,
                              hipStream_t stream) {
    const int2*  ind2 = (const int2*)d_in[0];
    const int2*  ind3 = (const int2*)d_in[1];
    const float* dist = (const float*)d_in[2];
    const float* diff = (const float*)d_in[3];
    const float* fc   = (const float*)d_in[5];
    float* out = (float*)d_out;

    const size_t seg_stride = (size_t)NSEG * sizeof(int2);
    const size_t need_min = OFF_CB + seg_stride * 608;

    if (ws_size >= need_min) {
        char* ws = (char*)d_ws;
        int* ccnt            = (int*)(ws + OFF_CCNT);
        int* ikmax           = (int*)(ws + OFF_IKMAX);
        unsigned short* aofp = (unsigned short*)(ws + OFF_AOFP);
        unsigned char* flag  = (unsigned char*)(ws + OFF_FLAG);
        int2* ovf            = (int2*)(ws + OFF_OVF);
        float4* pack         = (float4*)(ws + OFF_PACK);
        int2* cbucket        = (int2*)(ws + OFF_CB);
        int cap = (int)((ws_size - OFF_CB) / seg_stride);
        if (cap > 1024) cap = 1024;

        int pb = (N_PAIR + 255) / 256;
        prep2<<<pb, 256, 0, stream>>>(ind2, diff, fc, ccnt, ikmax, aofp, flag, pack, out);
        bin3<<<NTILES, 512, 0, stream>>>(ind3, aofp, ccnt, cbucket, ovf, cap);
        reduce9<<<NCB * 2, 256, 0, stream>>>(ccnt, cbucket, cap, pack, ikmax, flag, out);
        ovf3<<<OVF_CAP / 256, 256, 0, stream>>>(ccnt, ovf, pack, aofp, ikmax, flag, out);
        fin3<<<pb, 256, 0, stream>>>(ikmax, flag, aofp, out);
    } else {
        init_legacy<<<(N_PAIR + 255) / 256, 256, 0, stream>>>(out);
        tri_legacy<<<(N_TRI + 255) / 256, 256, 0, stream>>>((const int*)d_in[0], ind3, dist, diff, fc, out);
        fin_legacy<<<(N_PAIR + 255) / 256, 256, 0, stream>>>(out);
    }
}